// Round 3
// baseline (293.396 us; speedup 1.0000x reference)
//
#include <hip/hip_runtime.h>
#include <hip/hip_bf16.h>

#define T_DIM 2048
#define C_DIM 1024
#define NHEAD 16
#define DHEAD 64

typedef __attribute__((ext_vector_type(8))) short s16x8;   // 8 bf16 = 4 VGPRs
typedef __attribute__((ext_vector_type(4))) float f32x4;
typedef __attribute__((ext_vector_type(4))) unsigned short u16x4;

static __device__ __forceinline__ unsigned short f2bfu(float f){
  __hip_bfloat16 h = __float2bfloat16(f);   // RNE
  unsigned short u;
  __builtin_memcpy(&u, &h, 2);
  return u;
}

static __device__ __forceinline__ f32x4 MFMA16(s16x8 a, s16x8 b, f32x4 c){
  return __builtin_amdgcn_mfma_f32_16x16x32_bf16(a, b, c, 0, 0, 0);
}

// ---------- fp32 -> bf16 elementwise ----------
__global__ __launch_bounds__(256) void cvt_bf16_kernel(const float* __restrict__ in,
                                                       unsigned short* __restrict__ out, int n4){
  int i = blockIdx.x*256 + threadIdx.x;
  if (i < n4){
    float4 v = reinterpret_cast<const float4*>(in)[i];
    u16x4 o;
    o.x = f2bfu(v.x); o.y = f2bfu(v.y); o.z = f2bfu(v.z); o.w = f2bfu(v.w);
    reinterpret_cast<u16x4*>(out)[i] = o;
  }
}

// ---------- fp32 [K][N] -> bf16 [N][K] (transpose + convert) ----------
__global__ __launch_bounds__(256) void transpose_cvt_kernel(const float* __restrict__ src,
                                                            unsigned short* __restrict__ dst,
                                                            int K, int N){
  __shared__ unsigned short tile[64][65];
  int n0 = blockIdx.x*64, k0 = blockIdx.y*64;
  int tid = threadIdx.x;
  #pragma unroll
  for (int i=0;i<16;i++){
    int e = i*256 + tid; int r = e>>6, c = e&63;
    tile[r][c] = f2bfu(src[(size_t)(k0+r)*N + n0 + c]);
  }
  __syncthreads();
  #pragma unroll
  for (int i=0;i<16;i++){
    int e = i*256 + tid; int r = e>>6, c = e&63;
    dst[(size_t)(n0+r)*K + k0 + c] = tile[c][r];
  }
}

// ---------- int32 mask -> bitmask [T][T/32] words ----------
__global__ __launch_bounds__(256) void mask_bits_kernel(const int* __restrict__ m,
                                                        unsigned int* __restrict__ bits){
  int i = blockIdx.x*256 + threadIdx.x;
  unsigned long long b = __ballot(m[i] == 1);
  int lane = threadIdx.x & 63;
  if (lane == 0)  bits[i>>5] = (unsigned int)b;
  if (lane == 32) bits[i>>5] = (unsigned int)(b>>32);
}

// ---------- v [BH][T][64] -> vT [BH][64][T] ----------
__global__ __launch_bounds__(256) void transpose_v_kernel(const unsigned short* __restrict__ v,
                                                          unsigned short* __restrict__ vt){
  __shared__ unsigned short tile[64][65];
  int bh = blockIdx.y;
  int t0 = blockIdx.x*64;
  const unsigned short* src = v + (size_t)bh*T_DIM*DHEAD;
  unsigned short* dst = vt + (size_t)bh*T_DIM*DHEAD;
  int tid = threadIdx.x;
  #pragma unroll
  for (int i=0;i<16;i++){
    int e = i*256+tid; int r = e>>6, c = e&63;
    tile[r][c] = src[(size_t)(t0+r)*DHEAD + c];
  }
  __syncthreads();
  #pragma unroll
  for (int i=0;i<16;i++){
    int e = i*256+tid; int r = e>>6, c = e&63;
    dst[(size_t)r*T_DIM + t0 + c] = tile[c][r];
  }
}

// ---------- GEMM: C[M][N] = A[M][K] @ Bt[N][K]^T + bias ----------
// MODE 0: M=4096,N=3072 -> scatter q/k/v bf16 [B][H][T][64]
// MODE 1: M=4096,N=1024 -> fp32 out [M][N]
template<int MODE>
__global__ __launch_bounds__(256) void gemm_kernel(const unsigned short* __restrict__ A,
    const unsigned short* __restrict__ Bt, const float* __restrict__ bias,
    unsigned short* __restrict__ qo, unsigned short* __restrict__ ko,
    unsigned short* __restrict__ vo, float* __restrict__ out)
{
  const int K = 1024;
  __shared__ __align__(16) unsigned short As[128][72];  // +8 pad: 2-way bank alias (free)
  __shared__ __align__(16) unsigned short Bs[128][72];
  int tid = threadIdx.x;
  int lane = tid & 63, wave = tid >> 6;
  int m0 = blockIdx.y*128, n0 = blockIdx.x*128;
  int wm = (wave>>1)*64, wn = (wave&1)*64;
  int lr = lane & 15, lg = lane >> 4;
  f32x4 acc[4][4];
  #pragma unroll
  for (int i=0;i<4;i++){
    #pragma unroll
    for (int j=0;j<4;j++){
      #pragma unroll
      for (int r=0;r<4;r++) acc[i][j][r] = 0.f;
    }
  }
  for (int kt=0; kt<K; kt+=64){
    #pragma unroll
    for (int it=0; it<4; it++){
      int t = it*256 + tid;
      int r = t>>3, ch = (t&7)*8;
      *reinterpret_cast<s16x8*>(&As[r][ch]) =
          *reinterpret_cast<const s16x8*>(A + (size_t)(m0+r)*K + kt + ch);
      *reinterpret_cast<s16x8*>(&Bs[r][ch]) =
          *reinterpret_cast<const s16x8*>(Bt + (size_t)(n0+r)*K + kt + ch);
    }
    __syncthreads();
    #pragma unroll
    for (int kk=0; kk<2; kk++){
      s16x8 av[4], bv[4];
      #pragma unroll
      for (int i=0;i<4;i++){
        av[i] = *reinterpret_cast<const s16x8*>(&As[wm + i*16 + lr][kk*32 + lg*8]);
        bv[i] = *reinterpret_cast<const s16x8*>(&Bs[wn + i*16 + lr][kk*32 + lg*8]);
      }
      #pragma unroll
      for (int i=0;i<4;i++){
        #pragma unroll
        for (int j=0;j<4;j++)
          acc[i][j] = MFMA16(av[i], bv[j], acc[i][j]);
      }
    }
    __syncthreads();
  }
  // epilogue: C row = m0+wm+i*16+lg*4+r, col = n0+wn+j*16+lr  (m89-verified C/D layout)
  #pragma unroll
  for (int j=0;j<4;j++){
    int n = n0 + wn + j*16 + lr;
    float bvl = bias[n];
    #pragma unroll
    for (int i=0;i<4;i++){
      #pragma unroll
      for (int r=0;r<4;r++){
        int m = m0 + wm + i*16 + lg*4 + r;
        float val = acc[i][j][r] + bvl;
        if (MODE == 0){
          int which = n >> 10, c = n & 1023;
          int h = c >> 6, d = c & 63;
          int b = m >> 11, t = m & 2047;
          size_t idx = ((size_t)((b*NHEAD + h)*T_DIM + t))*DHEAD + d;
          unsigned short us = f2bfu(val);
          if (which == 0) qo[idx] = us;
          else if (which == 1) ko[idx] = us;
          else vo[idx] = us;
        } else {
          out[(size_t)m*C_DIM + n] = val;
        }
      }
    }
  }
}

// ---------- flash attention: 4 waves x 16 q-rows, KV tiles of 64 ----------
__global__ __launch_bounds__(256) void attn_kernel(const unsigned short* __restrict__ q,
    const unsigned short* __restrict__ k, const unsigned short* __restrict__ vt,
    const unsigned int* __restrict__ mbits, unsigned short* __restrict__ aout)
{
  __shared__ __align__(16) unsigned short Ks[64][72];
  __shared__ __align__(16) unsigned short Vs[64][72];      // Vs[d][kcol] (vT rows)
  __shared__ __align__(16) unsigned short Ps[4][16][72];   // per-wave P tile
  int bh = blockIdx.y;
  int q0 = blockIdx.x*64;
  int tid = threadIdx.x, lane = tid&63, wave = tid>>6;
  int lr = lane&15, lg = lane>>4;
  const unsigned short* qp = q  + (size_t)bh*T_DIM*DHEAD;
  const unsigned short* kp = k  + (size_t)bh*T_DIM*DHEAD;
  const unsigned short* vp = vt + (size_t)bh*T_DIM*DHEAD;
  int qw = q0 + wave*16;
  s16x8 qf[2];
  #pragma unroll
  for (int kk=0;kk<2;kk++)
    qf[kk] = *reinterpret_cast<const s16x8*>(qp + (size_t)(qw+lr)*DHEAD + kk*32 + lg*8);
  f32x4 o[4];
  #pragma unroll
  for (int cb=0;cb<4;cb++){
    #pragma unroll
    for (int r=0;r<4;r++) o[cb][r]=0.f;
  }
  float mrow[4], lrow[4];
  #pragma unroll
  for (int r=0;r<4;r++){ mrow[r] = -1e30f; lrow[r]=0.f; }
  int qbase = qw + lg*4;   // +r = this lane's global q-row (C-layout row)

  for (int k0=0; k0<T_DIM; k0+=64){
    #pragma unroll
    for (int it=0; it<2; it++){
      int t = it*256 + tid;
      int r = t>>3, ch = (t&7)*8;
      *reinterpret_cast<s16x8*>(&Ks[r][ch]) =
          *reinterpret_cast<const s16x8*>(kp + (size_t)(k0+r)*DHEAD + ch);
      *reinterpret_cast<s16x8*>(&Vs[r][ch]) =
          *reinterpret_cast<const s16x8*>(vp + (size_t)r*T_DIM + k0 + ch);
    }
    __syncthreads();
    // S = Q @ K^T  (identical lane->k load pattern for both operands)
    f32x4 s[4];
    #pragma unroll
    for (int cb=0;cb<4;cb++){
      f32x4 a;
      #pragma unroll
      for (int r=0;r<4;r++) a[r]=0.f;
      #pragma unroll
      for (int kk=0;kk<2;kk++){
        s16x8 kf = *reinterpret_cast<const s16x8*>(&Ks[cb*16 + lr][kk*32 + lg*8]);
        a = MFMA16(qf[kk], kf, a);
      }
      s[cb] = a;
    }
    // scale + mask (bit test; masked -> -1e30)
    #pragma unroll
    for (int cb=0;cb<4;cb++){
      int kc = k0 + cb*16 + lr;
      int w = kc >> 5, bit = kc & 31;
      #pragma unroll
      for (int r=0;r<4;r++){
        unsigned mw = mbits[(size_t)(qbase + r)*(T_DIM/32) + w];
        float val = s[cb][r]*0.125f;
        s[cb][r] = ((mw>>bit)&1u) ? -1e30f : val;
      }
    }
    // online softmax; row's 64 cols live in 4 cb slots x 16 lanes (same lg group)
    #pragma unroll
    for (int r=0;r<4;r++){
      float mx = fmaxf(fmaxf(s[0][r], s[1][r]), fmaxf(s[2][r], s[3][r]));
      mx = fmaxf(mx, __shfl_xor(mx, 1));
      mx = fmaxf(mx, __shfl_xor(mx, 2));
      mx = fmaxf(mx, __shfl_xor(mx, 4));
      mx = fmaxf(mx, __shfl_xor(mx, 8));
      float mnew = fmaxf(mrow[r], mx);
      float corr = __expf(mrow[r] - mnew);
      mrow[r] = mnew;
      float rs = 0.f;
      #pragma unroll
      for (int cb=0;cb<4;cb++){
        float p = __expf(s[cb][r] - mnew);
        s[cb][r] = p;
        rs += p;
      }
      rs += __shfl_xor(rs, 1);
      rs += __shfl_xor(rs, 2);
      rs += __shfl_xor(rs, 4);
      rs += __shfl_xor(rs, 8);
      lrow[r] = lrow[r]*corr + rs;
      #pragma unroll
      for (int cb=0;cb<4;cb++) o[cb][r] *= corr;
    }
    // P (C-layout) -> LDS -> A-fragment layout (wave-private, no barrier needed)
    #pragma unroll
    for (int cb=0;cb<4;cb++){
      #pragma unroll
      for (int r=0;r<4;r++)
        Ps[wave][lg*4 + r][cb*16 + lr] = f2bfu(s[cb][r]);
    }
    s16x8 pf[2];
    #pragma unroll
    for (int kk=0;kk<2;kk++)
      pf[kk] = *reinterpret_cast<const s16x8*>(&Ps[wave][lr][kk*32 + lg*8]);
    // O += P @ V   (B-fragment from Vs[d][k] rows: same k pattern as A)
    #pragma unroll
    for (int cb=0;cb<4;cb++){
      #pragma unroll
      for (int kk=0;kk<2;kk++){
        s16x8 vf = *reinterpret_cast<const s16x8*>(&Vs[cb*16 + lr][kk*32 + lg*8]);
        o[cb] = MFMA16(pf[kk], vf, o[cb]);
      }
    }
    __syncthreads();
  }
  int b = bh >> 4, h = bh & 15;
  #pragma unroll
  for (int r=0;r<4;r++){
    float inv = lrow[r] > 0.f ? 1.f/lrow[r] : 0.f;
    int row = b*T_DIM + qbase + r;
    #pragma unroll
    for (int cb=0;cb<4;cb++){
      int d = cb*16 + lr;
      aout[(size_t)row*C_DIM + h*DHEAD + d] = f2bfu(o[cb][r]*inv);
    }
  }
}

extern "C" void kernel_launch(void* const* d_in, const int* in_sizes, int n_in,
                              void* d_out, int out_size, void* d_ws, size_t ws_size,
                              hipStream_t stream){
  const float* x     = (const float*)d_in[0];
  const int*   mask  = (const int*)d_in[1];
  const float* Wqkv  = (const float*)d_in[2];
  const float* bqkv  = (const float*)d_in[3];
  const float* Wproj = (const float*)d_in[4];
  const float* bproj = (const float*)d_in[5];
  float* out = (float*)d_out;
  char* ws = (char*)d_ws;
  const size_t MB = (size_t)1<<20;
  unsigned short* xb     = (unsigned short*)(ws + 0*MB);   // 8MB  x bf16 [4096][1024]; aliased as aout later
  unsigned short* wqkvT  = (unsigned short*)(ws + 8*MB);   // 6MB  [3072][1024]
  unsigned short* wprojT = (unsigned short*)(ws + 14*MB);  // 2MB  [1024][1024]
  unsigned int*   mbits  = (unsigned int*)(ws + 16*MB);    // 512KB [2048][64] words
  unsigned short* qb     = (unsigned short*)(ws + 17*MB);  // 8MB  [2][16][2048][64]
  unsigned short* kb     = (unsigned short*)(ws + 25*MB);  // 8MB
  unsigned short* vb     = (unsigned short*)(ws + 33*MB);  // 8MB
  unsigned short* vtb    = (unsigned short*)(ws + 41*MB);  // 8MB  [2][16][64][2048]  (uses 49MB total)
  unsigned short* aout   = xb;  // safe alias: xb only read by gemm<0>, attn runs after

  cvt_bf16_kernel<<<dim3(4096), dim3(256), 0, stream>>>(x, xb, (2*2048*1024)/4);
  transpose_cvt_kernel<<<dim3(48,16), dim3(256), 0, stream>>>(Wqkv, wqkvT, 1024, 3072);
  transpose_cvt_kernel<<<dim3(16,16), dim3(256), 0, stream>>>(Wproj, wprojT, 1024, 1024);
  mask_bits_kernel<<<dim3((2048*2048)/256), dim3(256), 0, stream>>>(mask, mbits);
  gemm_kernel<0><<<dim3(24,32), dim3(256), 0, stream>>>(xb, wqkvT, bqkv, qb, kb, vb, nullptr);
  transpose_v_kernel<<<dim3(32,32), dim3(256), 0, stream>>>(vb, vtb);
  attn_kernel<<<dim3(32,32), dim3(256), 0, stream>>>(qb, kb, vtb, mbits, aout);
  gemm_kernel<1><<<dim3(8,32), dim3(256), 0, stream>>>(aout, wprojT, bproj, nullptr, nullptr, nullptr, out);
}

// Round 4
// 256.750 us; speedup vs baseline: 1.1427x; 1.1427x over previous
//
#include <hip/hip_runtime.h>
#include <hip/hip_bf16.h>

#define T_DIM 2048
#define C_DIM 1024
#define NHEAD 16
#define DHEAD 64

typedef __attribute__((ext_vector_type(8))) short s16x8;   // 8 bf16 = 4 VGPRs
typedef __attribute__((ext_vector_type(4))) short s16x4;   // 4 bf16 = 2 VGPRs
typedef __attribute__((ext_vector_type(4))) float f32x4;
typedef __attribute__((ext_vector_type(4))) unsigned short u16x4;

static __device__ __forceinline__ unsigned short f2bfu(float f){
  __hip_bfloat16 h = __float2bfloat16(f);   // RNE
  unsigned short u;
  __builtin_memcpy(&u, &h, 2);
  return u;
}

static __device__ __forceinline__ f32x4 MFMA16(s16x8 a, s16x8 b, f32x4 c){
  return __builtin_amdgcn_mfma_f32_16x16x32_bf16(a, b, c, 0, 0, 0);
}

// ---------- fp32 -> bf16 elementwise ----------
__global__ __launch_bounds__(256) void cvt_bf16_kernel(const float* __restrict__ in,
                                                       unsigned short* __restrict__ out, int n4){
  int i = blockIdx.x*256 + threadIdx.x;
  if (i < n4){
    float4 v = reinterpret_cast<const float4*>(in)[i];
    u16x4 o;
    o.x = f2bfu(v.x); o.y = f2bfu(v.y); o.z = f2bfu(v.z); o.w = f2bfu(v.w);
    reinterpret_cast<u16x4*>(out)[i] = o;
  }
}

// ---------- fp32 [K][N] -> bf16 [N][K] (transpose + convert) ----------
__global__ __launch_bounds__(256) void transpose_cvt_kernel(const float* __restrict__ src,
                                                            unsigned short* __restrict__ dst,
                                                            int K, int N){
  __shared__ unsigned short tile[64][65];
  int n0 = blockIdx.x*64, k0 = blockIdx.y*64;
  int tid = threadIdx.x;
  #pragma unroll
  for (int i=0;i<16;i++){
    int e = i*256 + tid; int r = e>>6, c = e&63;
    tile[r][c] = f2bfu(src[(size_t)(k0+r)*N + n0 + c]);
  }
  __syncthreads();
  #pragma unroll
  for (int i=0;i<16;i++){
    int e = i*256 + tid; int r = e>>6, c = e&63;
    dst[(size_t)(n0+r)*K + k0 + c] = tile[c][r];
  }
}

// ---------- int32 mask -> bitmask [T][T/32] words ----------
__global__ __launch_bounds__(256) void mask_bits_kernel(const int* __restrict__ m,
                                                        unsigned int* __restrict__ bits){
  int i = blockIdx.x*256 + threadIdx.x;
  unsigned long long b = __ballot(m[i] == 1);
  int lane = threadIdx.x & 63;
  if (lane == 0)  bits[i>>5] = (unsigned int)b;
  if (lane == 32) bits[i>>5] = (unsigned int)(b>>32);
}

// ---------- v [BH][T][64] -> vT [BH][64][T] ----------
__global__ __launch_bounds__(256) void transpose_v_kernel(const unsigned short* __restrict__ v,
                                                          unsigned short* __restrict__ vt){
  __shared__ unsigned short tile[64][65];
  int bh = blockIdx.y;
  int t0 = blockIdx.x*64;
  const unsigned short* src = v + (size_t)bh*T_DIM*DHEAD;
  unsigned short* dst = vt + (size_t)bh*T_DIM*DHEAD;
  int tid = threadIdx.x;
  #pragma unroll
  for (int i=0;i<16;i++){
    int e = i*256+tid; int r = e>>6, c = e&63;
    tile[r][c] = src[(size_t)(t0+r)*DHEAD + c];
  }
  __syncthreads();
  #pragma unroll
  for (int i=0;i<16;i++){
    int e = i*256+tid; int r = e>>6, c = e&63;
    dst[(size_t)r*T_DIM + t0 + c] = tile[c][r];
  }
}

// ---------- GEMM: C[M][N] = A[M][K] @ Bt[N][K]^T + bias ----------
// MODE 0: M=4096,N=3072 -> scatter q/k/v bf16 [B][H][T][64]
// MODE 1: M=4096,N=1024 -> fp32 out [M][N]
template<int MODE>
__global__ __launch_bounds__(256) void gemm_kernel(const unsigned short* __restrict__ A,
    const unsigned short* __restrict__ Bt, const float* __restrict__ bias,
    unsigned short* __restrict__ qo, unsigned short* __restrict__ ko,
    unsigned short* __restrict__ vo, float* __restrict__ out)
{
  const int K = 1024;
  __shared__ __align__(16) unsigned short As[128][72];  // +8 pad: 2-way bank alias (free)
  __shared__ __align__(16) unsigned short Bs[128][72];
  int tid = threadIdx.x;
  int lane = tid & 63, wave = tid >> 6;
  int m0 = blockIdx.y*128, n0 = blockIdx.x*128;
  int wm = (wave>>1)*64, wn = (wave&1)*64;
  int lr = lane & 15, lg = lane >> 4;
  f32x4 acc[4][4];
  #pragma unroll
  for (int i=0;i<4;i++){
    #pragma unroll
    for (int j=0;j<4;j++){
      #pragma unroll
      for (int r=0;r<4;r++) acc[i][j][r] = 0.f;
    }
  }
  for (int kt=0; kt<K; kt+=64){
    #pragma unroll
    for (int it=0; it<4; it++){
      int t = it*256 + tid;
      int r = t>>3, ch = (t&7)*8;
      *reinterpret_cast<s16x8*>(&As[r][ch]) =
          *reinterpret_cast<const s16x8*>(A + (size_t)(m0+r)*K + kt + ch);
      *reinterpret_cast<s16x8*>(&Bs[r][ch]) =
          *reinterpret_cast<const s16x8*>(Bt + (size_t)(n0+r)*K + kt + ch);
    }
    __syncthreads();
    #pragma unroll
    for (int kk=0; kk<2; kk++){
      s16x8 av[4], bv[4];
      #pragma unroll
      for (int i=0;i<4;i++){
        av[i] = *reinterpret_cast<const s16x8*>(&As[wm + i*16 + lr][kk*32 + lg*8]);
        bv[i] = *reinterpret_cast<const s16x8*>(&Bs[wn + i*16 + lr][kk*32 + lg*8]);
      }
      #pragma unroll
      for (int i=0;i<4;i++){
        #pragma unroll
        for (int j=0;j<4;j++)
          acc[i][j] = MFMA16(av[i], bv[j], acc[i][j]);
      }
    }
    __syncthreads();
  }
  // epilogue: C row = m0+wm+i*16+lg*4+r, col = n0+wn+j*16+lr  (m89-verified C/D layout)
  #pragma unroll
  for (int j=0;j<4;j++){
    int n = n0 + wn + j*16 + lr;
    float bvl = bias[n];
    #pragma unroll
    for (int i=0;i<4;i++){
      #pragma unroll
      for (int r=0;r<4;r++){
        int m = m0 + wm + i*16 + lg*4 + r;
        float val = acc[i][j][r] + bvl;
        if (MODE == 0){
          int which = n >> 10, c = n & 1023;
          int h = c >> 6, d = c & 63;
          int b = m >> 11, t = m & 2047;
          size_t idx = ((size_t)((b*NHEAD + h)*T_DIM + t))*DHEAD + d;
          unsigned short us = f2bfu(val);
          if (which == 0) qo[idx] = us;
          else if (which == 1) ko[idx] = us;
          else vo[idx] = us;
        } else {
          out[(size_t)m*C_DIM + n] = val;
        }
      }
    }
  }
}

// ---------- flash attention: 4 waves x 16 q-rows, KV tiles of 64 ----------
// Swapped QK^T: S^T = mfma(K,Q) -> lane owns q-row lr; softmax mostly in-lane.
__global__ __launch_bounds__(256) void attn_kernel(const unsigned short* __restrict__ q,
    const unsigned short* __restrict__ k, const unsigned short* __restrict__ vt,
    const unsigned int* __restrict__ mbits, unsigned short* __restrict__ aout)
{
  __shared__ __align__(16) unsigned short Ks[64][72];
  __shared__ __align__(16) unsigned short Vs[64][72];      // Vs[d][kcol] (vT rows)
  __shared__ __align__(16) unsigned short Ps[4][16][72];   // per-wave P tile [q=16][k=64+pad]
  int bh = blockIdx.y;
  int q0 = blockIdx.x*64;
  int tid = threadIdx.x, lane = tid&63, wave = tid>>6;
  int lr = lane&15, lg = lane>>4;
  const unsigned short* qp = q  + (size_t)bh*T_DIM*DHEAD;
  const unsigned short* kp = k  + (size_t)bh*T_DIM*DHEAD;
  const unsigned short* vp = vt + (size_t)bh*T_DIM*DHEAD;
  int qw = q0 + wave*16;
  s16x8 qf[2];
  #pragma unroll
  for (int kk=0;kk<2;kk++)
    qf[kk] = *reinterpret_cast<const s16x8*>(qp + (size_t)(qw+lr)*DHEAD + kk*32 + lg*8);
  f32x4 o[4];
  #pragma unroll
  for (int cb=0;cb<4;cb++){
    #pragma unroll
    for (int r=0;r<4;r++) o[cb][r]=0.f;
  }
  float m = -1e30f, l = 0.f;               // softmax state for q-row (qw + lr)
  const unsigned int* mptr = mbits + (size_t)(qw + lr)*(T_DIM/32);  // mask row (b,h-independent)

  for (int k0=0; k0<T_DIM; k0+=64){
    #pragma unroll
    for (int it=0; it<2; it++){
      int t = it*256 + tid;
      int r = t>>3, ch = (t&7)*8;
      *reinterpret_cast<s16x8*>(&Ks[r][ch]) =
          *reinterpret_cast<const s16x8*>(kp + (size_t)(k0+r)*DHEAD + ch);
      *reinterpret_cast<s16x8*>(&Vs[r][ch]) =
          *reinterpret_cast<const s16x8*>(vp + (size_t)r*T_DIM + k0 + ch);
    }
    __syncthreads();
    // S^T = K @ Q^T : st[cb] row = k_local = cb*16+lg*4+reg, col = q = lr
    f32x4 st[4];
    #pragma unroll
    for (int cb=0;cb<4;cb++){
      f32x4 a;
      #pragma unroll
      for (int r=0;r<4;r++) a[r]=0.f;
      #pragma unroll
      for (int kk=0;kk<2;kk++){
        s16x8 kf = *reinterpret_cast<const s16x8*>(&Ks[cb*16 + lr][kk*32 + lg*8]);
        a = MFMA16(kf, qf[kk], a);   // A=K rows, B=Q rows
      }
      st[cb] = a;
    }
    // scale + mask: lane's k's = k0 + 16cb + 4lg + reg -> only 2 mask words per lane
    unsigned mw0 = mptr[(k0>>5)];
    unsigned mw1 = mptr[(k0>>5)+1];
    #pragma unroll
    for (int cb=0;cb<4;cb++){
      unsigned msel = (cb<2) ? mw0 : mw1;
      unsigned ms = msel >> ((cb&1)*16 + lg*4);
      #pragma unroll
      for (int r=0;r<4;r++){
        float val = st[cb][r]*0.125f;
        st[cb][r] = ((ms>>r)&1u) ? -1e30f : val;
      }
    }
    // online softmax for q-row lr: 16 in-lane values + 2 cross-lg shuffles
    float pmax = st[0][0];
    #pragma unroll
    for (int cb=0;cb<4;cb++){
      #pragma unroll
      for (int r=0;r<4;r++) pmax = fmaxf(pmax, st[cb][r]);
    }
    pmax = fmaxf(pmax, __shfl_xor(pmax, 16));
    pmax = fmaxf(pmax, __shfl_xor(pmax, 32));
    float mnew = fmaxf(m, pmax);
    float corr = __expf(m - mnew);
    m = mnew;
    float rs = 0.f;
    #pragma unroll
    for (int cb=0;cb<4;cb++){
      #pragma unroll
      for (int r=0;r<4;r++){
        float p = __expf(st[cb][r] - mnew);
        st[cb][r] = p;
        rs += p;
      }
    }
    rs += __shfl_xor(rs, 16);
    rs += __shfl_xor(rs, 32);
    l = l*corr + rs;
    // rescale O (O rows are q = qw + lg*4 + r; fetch corr from the lane owning that row)
    float corrO[4];
    #pragma unroll
    for (int r=0;r<4;r++) corrO[r] = __shfl(corr, lg*4 + r);
    #pragma unroll
    for (int cb=0;cb<4;cb++){
      #pragma unroll
      for (int r=0;r<4;r++) o[cb][r] *= corrO[r];
    }
    // P^T lane-local: P[q=lr][k=16cb+4lg+reg], reg-consecutive k -> packed b64 writes
    #pragma unroll
    for (int cb=0;cb<4;cb++){
      s16x4 pk;
      #pragma unroll
      for (int r=0;r<4;r++) pk[r] = (short)f2bfu(st[cb][r]);
      *reinterpret_cast<s16x4*>(&Ps[wave][lr][cb*16 + lg*4]) = pk;
    }
    s16x8 pf[2];
    #pragma unroll
    for (int kk=0;kk<2;kk++)
      pf[kk] = *reinterpret_cast<const s16x8*>(&Ps[wave][lr][kk*32 + lg*8]);
    // O += P @ V   (B-fragment from Vs[d][k] rows: same k pattern as A)
    #pragma unroll
    for (int cb=0;cb<4;cb++){
      #pragma unroll
      for (int kk=0;kk<2;kk++){
        s16x8 vf = *reinterpret_cast<const s16x8*>(&Vs[cb*16 + lr][kk*32 + lg*8]);
        o[cb] = MFMA16(pf[kk], vf, o[cb]);
      }
    }
    __syncthreads();
  }
  int b = bh >> 4, h = bh & 15;
  float inv = l > 0.f ? 1.f/l : 0.f;       // for q-row lr
  #pragma unroll
  for (int r=0;r<4;r++){
    float invO = __shfl(inv, lg*4 + r);
    int row = b*T_DIM + qw + lg*4 + r;
    #pragma unroll
    for (int cb=0;cb<4;cb++){
      int d = cb*16 + lr;
      aout[(size_t)row*C_DIM + h*DHEAD + d] = f2bfu(o[cb][r]*invO);
    }
  }
}

extern "C" void kernel_launch(void* const* d_in, const int* in_sizes, int n_in,
                              void* d_out, int out_size, void* d_ws, size_t ws_size,
                              hipStream_t stream){
  const float* x     = (const float*)d_in[0];
  const int*   mask  = (const int*)d_in[1];
  const float* Wqkv  = (const float*)d_in[2];
  const float* bqkv  = (const float*)d_in[3];
  const float* Wproj = (const float*)d_in[4];
  const float* bproj = (const float*)d_in[5];
  float* out = (float*)d_out;
  char* ws = (char*)d_ws;
  const size_t MB = (size_t)1<<20;
  unsigned short* xb     = (unsigned short*)(ws + 0*MB);   // 8MB  x bf16 [4096][1024]; aliased as aout later
  unsigned short* wqkvT  = (unsigned short*)(ws + 8*MB);   // 6MB  [3072][1024]
  unsigned short* wprojT = (unsigned short*)(ws + 14*MB);  // 2MB  [1024][1024]
  unsigned int*   mbits  = (unsigned int*)(ws + 16*MB);    // 512KB [2048][64] words
  unsigned short* qb     = (unsigned short*)(ws + 17*MB);  // 8MB  [2][16][2048][64]
  unsigned short* kb     = (unsigned short*)(ws + 25*MB);  // 8MB
  unsigned short* vb     = (unsigned short*)(ws + 33*MB);  // 8MB
  unsigned short* vtb    = (unsigned short*)(ws + 41*MB);  // 8MB  [2][16][64][2048]  (uses 49MB total)
  unsigned short* aout   = xb;  // safe alias: xb only read by gemm<0>, attn runs after

  cvt_bf16_kernel<<<dim3(4096), dim3(256), 0, stream>>>(x, xb, (2*2048*1024)/4);
  transpose_cvt_kernel<<<dim3(48,16), dim3(256), 0, stream>>>(Wqkv, wqkvT, 1024, 3072);
  transpose_cvt_kernel<<<dim3(16,16), dim3(256), 0, stream>>>(Wproj, wprojT, 1024, 1024);
  mask_bits_kernel<<<dim3((2048*2048)/256), dim3(256), 0, stream>>>(mask, mbits);
  gemm_kernel<0><<<dim3(24,32), dim3(256), 0, stream>>>(xb, wqkvT, bqkv, qb, kb, vb, nullptr);
  transpose_v_kernel<<<dim3(32,32), dim3(256), 0, stream>>>(vb, vtb);
  attn_kernel<<<dim3(32,32), dim3(256), 0, stream>>>(qb, kb, vtb, mbits, aout);
  gemm_kernel<1><<<dim3(8,32), dim3(256), 0, stream>>>(aout, wprojT, bproj, nullptr, nullptr, nullptr, out);
}